// Round 2
// baseline (3388.722 us; speedup 1.0000x reference)
//
#include <hip/hip_runtime.h>
#include <hip/hip_bf16.h>

// Sizes (fixed problem): N=100000 nodes, E=600000 edges, H=128, Z=64, IN=6, BIN=198.

__global__ __launch_bounds__(256) void k_edge0(
    const int* __restrict__ edges, const float* __restrict__ vert,
    const float* __restrict__ vp, float* __restrict__ deg,
    float* __restrict__ msg_in, int nE) {
  int e = blockIdx.x * blockDim.x + threadIdx.x;
  if (e >= nE) return;
  int src = edges[2 * e], dst = edges[2 * e + 1];
  atomicAdd(&deg[dst], 1.0f);
#pragma unroll
  for (int k = 0; k < 3; ++k) {
    atomicAdd(&msg_in[dst * 6 + k], vert[src * 3 + k]);
    atomicAdd(&msg_in[dst * 6 + 3 + k], vp[src * 3 + k]);
  }
}

__global__ __launch_bounds__(256) void k_invdeg(
    float* __restrict__ deg, const float* __restrict__ msg_in,
    float* __restrict__ nb_in, int nN) {
  int n = blockIdx.x * blockDim.x + threadIdx.x;
  if (n >= nN) return;
  float inv = 1.0f / fmaxf(deg[n], 1.0f);
  deg[n] = inv;  // deg buffer becomes inv_deg
#pragma unroll
  for (int k = 0; k < 6; ++k) nb_in[n * 6 + k] = msg_in[n * 6 + k] * inv;
}

__global__ __launch_bounds__(256) void k_layer0(
    const float* __restrict__ vert, const float* __restrict__ vp,
    const float* __restrict__ nb_in, const float* __restrict__ W0s,
    const float* __restrict__ W0n, const float* __restrict__ b0,
    float* __restrict__ f, int nN) {
  int t = blockIdx.x * blockDim.x + threadIdx.x;
  int n = t >> 7, h = t & 127;
  if (n >= nN) return;
  float acc = b0[h];
#pragma unroll
  for (int k = 0; k < 3; ++k) {
    acc += vert[n * 3 + k] * W0s[k * 128 + h];
    acc += vp[n * 3 + k] * W0s[(3 + k) * 128 + h];
    acc += nb_in[n * 6 + k] * W0n[k * 128 + h];
    acc += nb_in[n * 6 + 3 + k] * W0n[(3 + k) * 128 + h];
  }
  f[(size_t)n * 128 + h] = fmaxf(acc, 0.0f);
}

template <int WITH_Z>
__global__ __launch_bounds__(256) void k_scatter(
    const float* __restrict__ f, const float* __restrict__ z,
    const int* __restrict__ edges, float* __restrict__ msg,
    float* __restrict__ msg_z, int nE) {
  int w = (blockIdx.x * 256 + threadIdx.x) >> 6;
  int lane = threadIdx.x & 63;
  if (w >= nE) return;
  int src = edges[2 * w], dst = edges[2 * w + 1];
  atomicAdd(&msg[(size_t)dst * 128 + lane], f[(size_t)src * 128 + lane]);
  atomicAdd(&msg[(size_t)dst * 128 + 64 + lane], f[(size_t)src * 128 + 64 + lane]);
  if (WITH_Z)
    atomicAdd(&msg_z[(size_t)dst * 64 + lane], z[(size_t)src * 64 + lane]);
}

// Mid layer: f_new = relu([f, z_i, in] @ Ws + [nb_f, nb_z_i, nb_in] @ Wn + b)
// Virtual X row (396): [0..127]=f, [128..191]=z, [192..197]=in,
//                      [198..325]=nb_f, [326..389]=nb_z, [390..395]=nb_in
#define BM 32
__global__ __launch_bounds__(256) void k_gemm_mid(
    float* __restrict__ f, const float* __restrict__ z,
    const float* __restrict__ vert, const float* __restrict__ vp,
    const float* __restrict__ nb_in, const float* __restrict__ msg,
    const float* __restrict__ msg_z, const float* __restrict__ inv_deg,
    const float* __restrict__ Ws, const float* __restrict__ Wn,
    const float* __restrict__ bias, int nN) {
  __shared__ float xs[BM][400];
  int t = threadIdx.x;
  int n0 = blockIdx.x * BM;

  for (int i = t; i < BM * 128; i += 256) {
    int node = i >> 7, k = i & 127;
    int gn = n0 + node; if (gn >= nN) gn = nN - 1;
    float inv = inv_deg[gn];
    xs[node][k] = f[(size_t)gn * 128 + k];
    xs[node][198 + k] = msg[(size_t)gn * 128 + k] * inv;
  }
  for (int i = t; i < BM * 64; i += 256) {
    int node = i >> 6, k = i & 63;
    int gn = n0 + node; if (gn >= nN) gn = nN - 1;
    float inv = inv_deg[gn];
    xs[node][128 + k] = z[(size_t)gn * 64 + k];
    xs[node][326 + k] = msg_z[(size_t)gn * 64 + k] * inv;
  }
  if (t < BM * 6) {
    int node = t / 6, k = t % 6;
    int gn = n0 + node; if (gn >= nN) gn = nN - 1;
    xs[node][192 + k] = (k < 3) ? vert[gn * 3 + k] : vp[gn * 3 + k - 3];
    xs[node][390 + k] = nb_in[gn * 6 + k];
  }
  __syncthreads();

  int tx = t & 31;   // h = tx*4 .. tx*4+3
  int ty = t >> 5;   // nodes ty*4 .. ty*4+3
  float4 bv = reinterpret_cast<const float4*>(bias)[tx];
  float acc[4][4];
#pragma unroll
  for (int i = 0; i < 4; ++i) {
    acc[i][0] = bv.x; acc[i][1] = bv.y; acc[i][2] = bv.z; acc[i][3] = bv.w;
  }
  const float4* Ws4 = reinterpret_cast<const float4*>(Ws);
  const float4* Wn4 = reinterpret_cast<const float4*>(Wn);
#pragma unroll 2
  for (int k = 0; k < 198; ++k) {
    float4 w = Ws4[k * 32 + tx];
#pragma unroll
    for (int i = 0; i < 4; ++i) {
      float xv = xs[ty * 4 + i][k];
      acc[i][0] += xv * w.x; acc[i][1] += xv * w.y;
      acc[i][2] += xv * w.z; acc[i][3] += xv * w.w;
    }
  }
#pragma unroll 2
  for (int k = 0; k < 198; ++k) {
    float4 w = Wn4[k * 32 + tx];
#pragma unroll
    for (int i = 0; i < 4; ++i) {
      float xv = xs[ty * 4 + i][198 + k];
      acc[i][0] += xv * w.x; acc[i][1] += xv * w.y;
      acc[i][2] += xv * w.z; acc[i][3] += xv * w.w;
    }
  }
#pragma unroll
  for (int i = 0; i < 4; ++i) {
    int gn = n0 + ty * 4 + i;
    if (gn < nN) {
      float4 o;
      o.x = fmaxf(acc[i][0], 0.0f); o.y = fmaxf(acc[i][1], 0.0f);
      o.z = fmaxf(acc[i][2], 0.0f); o.w = fmaxf(acc[i][3], 0.0f);
      reinterpret_cast<float4*>(f)[(size_t)gn * 32 + tx] = o;
    }
  }
}

__global__ __launch_bounds__(64) void k_final(
    const float* __restrict__ f, const float* __restrict__ msg,
    const float* __restrict__ inv_deg, const float* __restrict__ Wls,
    const float* __restrict__ Wln, const float* __restrict__ bl,
    float* __restrict__ out, int nN) {
  int n = blockIdx.x;
  int l = threadIdx.x;
  float inv = inv_deg[n];
  float a0 = f[(size_t)n * 128 + l], a1 = f[(size_t)n * 128 + 64 + l];
  float m0 = msg[(size_t)n * 128 + l] * inv, m1 = msg[(size_t)n * 128 + 64 + l] * inv;
  float p[3];
#pragma unroll
  for (int o = 0; o < 3; ++o)
    p[o] = a0 * Wls[l * 3 + o] + a1 * Wls[(64 + l) * 3 + o] +
           m0 * Wln[l * 3 + o] + m1 * Wln[(64 + l) * 3 + o];
#pragma unroll
  for (int off = 32; off >= 1; off >>= 1) {
    p[0] += __shfl_xor(p[0], off);
    p[1] += __shfl_xor(p[1], off);
    p[2] += __shfl_xor(p[2], off);
  }
  if (l == 0) {
    out[n * 3 + 0] = p[0] + bl[0];
    out[n * 3 + 1] = p[1] + bl[1];
    out[n * 3 + 2] = p[2] + bl[2];
  }
}

extern "C" void kernel_launch(void* const* d_in, const int* in_sizes, int n_in,
                              void* d_out, int out_size, void* d_ws, size_t ws_size,
                              hipStream_t stream) {
  const float* vert = (const float*)d_in[0];
  const int* edges = (const int*)d_in[1];
  const float* vp = (const float*)d_in[2];
  const float* z = (const float*)d_in[3];
  const float* W0s = (const float*)d_in[4];
  const float* W0n = (const float*)d_in[5];
  const float* b0 = (const float*)d_in[6];
  const float* Wbs = (const float*)d_in[7];
  const float* Wbn = (const float*)d_in[8];
  const float* bb = (const float*)d_in[9];
  const float* Wls = (const float*)d_in[10];
  const float* Wln = (const float*)d_in[11];
  const float* bl = (const float*)d_in[12];
  int nN = in_sizes[0] / 3;
  int nE = in_sizes[1] / 2;

  float* ws = (float*)d_ws;
  size_t o = 0;
  float* deg = ws + o; o += (size_t)nN;          // becomes inv_deg
  float* msg_in = ws + o; o += (size_t)nN * 6;   // contiguous with deg (single memset)
  float* nb_in = ws + o; o += (size_t)nN * 6;
  float* f = ws + o; o += (size_t)nN * 128;
  float* msg = ws + o; o += (size_t)nN * 128;    // msg_z contiguous after msg
  float* msg_z = ws + o; o += (size_t)nN * 64;

  // deg + msg_in zero (contiguous: nN*7 floats)
  hipMemsetAsync(deg, 0, (size_t)nN * 7 * sizeof(float), stream);
  k_edge0<<<(nE + 255) / 256, 256, 0, stream>>>(edges, vert, vp, deg, msg_in, nE);
  k_invdeg<<<(nN + 255) / 256, 256, 0, stream>>>(deg, msg_in, nb_in, nN);
  k_layer0<<<(int)(((size_t)nN * 128 + 255) / 256), 256, 0, stream>>>(
      vert, vp, nb_in, W0s, W0n, b0, f, nN);

  for (int i = 0; i < 4; ++i) {
    // msg + msg_z zero (contiguous: nN*192 floats)
    hipMemsetAsync(msg, 0, (size_t)nN * 192 * sizeof(float), stream);
    k_scatter<1><<<(int)(((size_t)nE * 64 + 255) / 256), 256, 0, stream>>>(
        f, z + (size_t)i * nN * 64, edges, msg, msg_z, nE);
    k_gemm_mid<<<(nN + BM - 1) / BM, 256, 0, stream>>>(
        f, z + (size_t)i * nN * 64, vert, vp, nb_in, msg, msg_z, deg,
        Wbs + (size_t)i * 198 * 128, Wbn + (size_t)i * 198 * 128, bb + i * 128, nN);
  }

  hipMemsetAsync(msg, 0, (size_t)nN * 128 * sizeof(float), stream);
  k_scatter<0><<<(int)(((size_t)nE * 64 + 255) / 256), 256, 0, stream>>>(
      f, nullptr, edges, msg, nullptr, nE);
  k_final<<<nN, 64, 0, stream>>>(f, msg, deg, Wls, Wln, bl, (float*)d_out, nN);
}

// Round 3
// 1446.287 us; speedup vs baseline: 2.3430x; 2.3430x over previous
//
#include <hip/hip_runtime.h>
#include <hip/hip_bf16.h>

// N=100000 nodes, E=600000 edges, H=128, Z=64, IN=6. K per GEMM = 198.
// Key algebra: D^-1 (A x) @ Wn == D^-1 A (x @ Wn)  -> aggregate 128 feats, not 198
// (and only 3 feats for the final layer). Aggregation via CSR gather, no atomics.

// ---------------- CSR build ----------------
__global__ __launch_bounds__(256) void k_hist(
    const int* __restrict__ edges, int* __restrict__ count, int nE) {
  int e = blockIdx.x * blockDim.x + threadIdx.x;
  if (e >= nE) return;
  atomicAdd(&count[edges[2 * e + 1]], 1);
}

__global__ __launch_bounds__(256) void k_scan_part(
    const int* __restrict__ count, int* __restrict__ partial, int nN) {
  __shared__ int s[256];
  int t = threadIdx.x;
  int n = blockIdx.x * 256 + t;
  s[t] = (n < nN) ? count[n] : 0;
  __syncthreads();
  for (int off = 128; off > 0; off >>= 1) {
    if (t < off) s[t] += s[t + off];
    __syncthreads();
  }
  if (t == 0) partial[blockIdx.x] = s[0];
}

__global__ __launch_bounds__(512) void k_scan_mid(
    int* __restrict__ partial, int* __restrict__ row_ptr, int nb, int nN, int nE) {
  __shared__ int s[512];
  int t = threadIdx.x;
  int v = (t < nb) ? partial[t] : 0;
  s[t] = v;
  __syncthreads();
  for (int off = 1; off < 512; off <<= 1) {
    int add = (t >= off) ? s[t - off] : 0;
    __syncthreads();
    s[t] += add;
    __syncthreads();
  }
  if (t < nb) partial[t] = s[t] - v;  // exclusive
  if (t == 0) row_ptr[nN] = nE;
}

__global__ __launch_bounds__(256) void k_scan_out(
    const int* __restrict__ count, const int* __restrict__ partial,
    int* __restrict__ row_ptr, int* __restrict__ cursor,
    float* __restrict__ invdeg, int nN) {
  __shared__ int s[256];
  int t = threadIdx.x;
  int n = blockIdx.x * 256 + t;
  int v = (n < nN) ? count[n] : 0;
  s[t] = v;
  __syncthreads();
  for (int off = 1; off < 256; off <<= 1) {
    int add = (t >= off) ? s[t - off] : 0;
    __syncthreads();
    s[t] += add;
    __syncthreads();
  }
  if (n < nN) {
    int excl = s[t] - v + partial[blockIdx.x];
    row_ptr[n] = excl;
    cursor[n] = excl;
    invdeg[n] = 1.0f / fmaxf((float)v, 1.0f);
  }
}

__global__ __launch_bounds__(256) void k_fill(
    const int* __restrict__ edges, int* __restrict__ cursor,
    int* __restrict__ csr_src, int nE) {
  int e = blockIdx.x * blockDim.x + threadIdx.x;
  if (e >= nE) return;
  int src = edges[2 * e], dst = edges[2 * e + 1];
  int pos = atomicAdd(&cursor[dst], 1);
  csr_src[pos] = src;
}

// ---------------- input-feature aggregation (6 feats) ----------------
__global__ __launch_bounds__(256) void k_nbin(
    const int* __restrict__ row_ptr, const int* __restrict__ csr_src,
    const float* __restrict__ vert, const float* __restrict__ vp,
    const float* __restrict__ invdeg, float* __restrict__ nb_in, int nN) {
  int n = blockIdx.x * blockDim.x + threadIdx.x;
  if (n >= nN) return;
  float a[6] = {0, 0, 0, 0, 0, 0};
  int beg = row_ptr[n], end = row_ptr[n + 1];
  for (int j = beg; j < end; ++j) {
    int s = csr_src[j];
#pragma unroll
    for (int k = 0; k < 3; ++k) {
      a[k] += vert[s * 3 + k];
      a[3 + k] += vp[s * 3 + k];
    }
  }
  float inv = invdeg[n];
#pragma unroll
  for (int k = 0; k < 6; ++k) nb_in[n * 6 + k] = a[k] * inv;
}

// ---------------- layer 0 ----------------
__global__ __launch_bounds__(256) void k_layer0(
    const float* __restrict__ vert, const float* __restrict__ vp,
    const float* __restrict__ nb_in, const float* __restrict__ W0s,
    const float* __restrict__ W0n, const float* __restrict__ b0,
    float* __restrict__ f, int nN) {
  int t = blockIdx.x * blockDim.x + threadIdx.x;
  int n = t >> 7, hh = t & 127;
  if (n >= nN) return;
  float acc = b0[hh];
#pragma unroll
  for (int k = 0; k < 3; ++k) {
    acc += vert[n * 3 + k] * W0s[k * 128 + hh];
    acc += vp[n * 3 + k] * W0s[(3 + k) * 128 + hh];
    acc += nb_in[n * 6 + k] * W0n[k * 128 + hh];
    acc += nb_in[n * 6 + 3 + k] * W0n[(3 + k) * 128 + hh];
  }
  f[(size_t)n * 128 + hh] = fmaxf(acc, 0.0f);
}

// ---------------- mid-layer GEMM: out = x@W (+nb+b, relu) ----------------
// x = [f(128), z(64), vert(3), vp(3)] staged in LDS. K=198.
template <int WRITE_H>
__global__ __launch_bounds__(256) void k_gemm(
    float* f, float* __restrict__ h, const float* __restrict__ z,
    const float* __restrict__ vert, const float* __restrict__ vp,
    const float* __restrict__ nb, const float* __restrict__ W,
    const float* __restrict__ bias, int nN) {
  __shared__ float xs[32][200];
  int t = threadIdx.x;
  int n0 = blockIdx.x * 32;

  for (int i = t; i < 32 * 128; i += 256) {
    int node = i >> 7, k = i & 127;
    int gn = min(n0 + node, nN - 1);
    xs[node][k] = f[(size_t)gn * 128 + k];
  }
  for (int i = t; i < 32 * 64; i += 256) {
    int node = i >> 6, k = i & 63;
    int gn = min(n0 + node, nN - 1);
    xs[node][128 + k] = z[(size_t)gn * 64 + k];
  }
  if (t < 32 * 6) {
    int node = t / 6, k = t % 6;
    int gn = min(n0 + node, nN - 1);
    xs[node][192 + k] = (k < 3) ? vert[gn * 3 + k] : vp[gn * 3 + k - 3];
  }
  __syncthreads();

  int tx = t & 31;   // 4 h-cols: tx*4..tx*4+3
  int ty = t >> 5;   // 4 nodes: ty*4..ty*4+3
  float acc[4][4];
  if (WRITE_H) {
#pragma unroll
    for (int i = 0; i < 4; ++i)
      acc[i][0] = acc[i][1] = acc[i][2] = acc[i][3] = 0.0f;
  } else {
    float4 bv = reinterpret_cast<const float4*>(bias)[tx];
#pragma unroll
    for (int i = 0; i < 4; ++i) {
      int gn = min(n0 + ty * 4 + i, nN - 1);
      float4 nv = reinterpret_cast<const float4*>(nb)[(size_t)gn * 32 + tx];
      acc[i][0] = bv.x + nv.x; acc[i][1] = bv.y + nv.y;
      acc[i][2] = bv.z + nv.z; acc[i][3] = bv.w + nv.w;
    }
  }
  const float4* W4 = reinterpret_cast<const float4*>(W);
#pragma unroll 2
  for (int k = 0; k < 198; ++k) {
    float4 w = W4[k * 32 + tx];
#pragma unroll
    for (int i = 0; i < 4; ++i) {
      float xv = xs[ty * 4 + i][k];
      acc[i][0] += xv * w.x; acc[i][1] += xv * w.y;
      acc[i][2] += xv * w.z; acc[i][3] += xv * w.w;
    }
  }
#pragma unroll
  for (int i = 0; i < 4; ++i) {
    int gn = n0 + ty * 4 + i;
    if (gn < nN) {
      if (WRITE_H) {
        float4 o = {acc[i][0], acc[i][1], acc[i][2], acc[i][3]};
        reinterpret_cast<float4*>(h)[(size_t)gn * 32 + tx] = o;
      } else {
        float4 o;
        o.x = fmaxf(acc[i][0], 0.0f); o.y = fmaxf(acc[i][1], 0.0f);
        o.z = fmaxf(acc[i][2], 0.0f); o.w = fmaxf(acc[i][3], 0.0f);
        reinterpret_cast<float4*>(f)[(size_t)gn * 32 + tx] = o;
      }
    }
  }
}

// ---------------- gather-aggregate h (128 feats), invdeg folded ----------------
__global__ __launch_bounds__(256) void k_gather128(
    const float4* __restrict__ h4, const int* __restrict__ row_ptr,
    const int* __restrict__ csr_src, const float* __restrict__ invdeg,
    float4* __restrict__ nb4, int nN) {
  int t = blockIdx.x * 256 + threadIdx.x;
  int n = t >> 5, c = t & 31;
  if (n >= nN) return;
  int beg = row_ptr[n], end = row_ptr[n + 1];
  float4 acc = {0, 0, 0, 0};
  for (int j = beg; j < end; ++j) {
    int s = csr_src[j];
    float4 v = h4[(size_t)s * 32 + c];
    acc.x += v.x; acc.y += v.y; acc.z += v.z; acc.w += v.w;
  }
  float inv = invdeg[n];
  float4 o = {acc.x * inv, acc.y * inv, acc.z * inv, acc.w * inv};
  nb4[(size_t)n * 32 + c] = o;
}

// ---------------- final layer ----------------
__global__ __launch_bounds__(256) void k_final_h(
    const float* __restrict__ f, const float* __restrict__ Wln,
    float4* __restrict__ h3, int nN) {
  int n = blockIdx.x * 4 + (threadIdx.x >> 6);
  int l = threadIdx.x & 63;
  if (n >= nN) return;
  float a0 = f[(size_t)n * 128 + l], a1 = f[(size_t)n * 128 + 64 + l];
  float p[3];
#pragma unroll
  for (int o = 0; o < 3; ++o)
    p[o] = a0 * Wln[l * 3 + o] + a1 * Wln[(64 + l) * 3 + o];
#pragma unroll
  for (int off = 32; off >= 1; off >>= 1) {
    p[0] += __shfl_xor(p[0], off);
    p[1] += __shfl_xor(p[1], off);
    p[2] += __shfl_xor(p[2], off);
  }
  if (l == 0) {
    float4 o = {p[0], p[1], p[2], 0.0f};
    h3[n] = o;
  }
}

__global__ __launch_bounds__(256) void k_gather3(
    const float4* __restrict__ h3, const int* __restrict__ row_ptr,
    const int* __restrict__ csr_src, const float* __restrict__ invdeg,
    float4* __restrict__ nb3, int nN) {
  int n = blockIdx.x * 256 + threadIdx.x;
  if (n >= nN) return;
  int beg = row_ptr[n], end = row_ptr[n + 1];
  float4 acc = {0, 0, 0, 0};
  for (int j = beg; j < end; ++j) {
    float4 v = h3[csr_src[j]];
    acc.x += v.x; acc.y += v.y; acc.z += v.z;
  }
  float inv = invdeg[n];
  float4 o = {acc.x * inv, acc.y * inv, acc.z * inv, 0.0f};
  nb3[n] = o;
}

__global__ __launch_bounds__(256) void k_final_out(
    const float* __restrict__ f, const float* __restrict__ Wls,
    const float4* __restrict__ nb3, const float* __restrict__ bl,
    float* __restrict__ out, int nN) {
  int n = blockIdx.x * 4 + (threadIdx.x >> 6);
  int l = threadIdx.x & 63;
  if (n >= nN) return;
  float a0 = f[(size_t)n * 128 + l], a1 = f[(size_t)n * 128 + 64 + l];
  float p[3];
#pragma unroll
  for (int o = 0; o < 3; ++o)
    p[o] = a0 * Wls[l * 3 + o] + a1 * Wls[(64 + l) * 3 + o];
#pragma unroll
  for (int off = 32; off >= 1; off >>= 1) {
    p[0] += __shfl_xor(p[0], off);
    p[1] += __shfl_xor(p[1], off);
    p[2] += __shfl_xor(p[2], off);
  }
  if (l == 0) {
    float4 nv = nb3[n];
    out[n * 3 + 0] = p[0] + nv.x + bl[0];
    out[n * 3 + 1] = p[1] + nv.y + bl[1];
    out[n * 3 + 2] = p[2] + nv.z + bl[2];
  }
}

extern "C" void kernel_launch(void* const* d_in, const int* in_sizes, int n_in,
                              void* d_out, int out_size, void* d_ws, size_t ws_size,
                              hipStream_t stream) {
  const float* vert = (const float*)d_in[0];
  const int* edges = (const int*)d_in[1];
  const float* vp = (const float*)d_in[2];
  const float* z = (const float*)d_in[3];
  const float* W0s = (const float*)d_in[4];
  const float* W0n = (const float*)d_in[5];
  const float* b0 = (const float*)d_in[6];
  const float* Wbs = (const float*)d_in[7];
  const float* Wbn = (const float*)d_in[8];
  const float* bb = (const float*)d_in[9];
  const float* Wls = (const float*)d_in[10];
  const float* Wln = (const float*)d_in[11];
  const float* bl = (const float*)d_in[12];
  int nN = in_sizes[0] / 3;
  int nE = in_sizes[1] / 2;

  float* ws = (float*)d_ws;
  size_t o = 0;
  float* invdeg = ws + o; o += (size_t)nN;
  float* nb_in = ws + o; o += (size_t)nN * 6;
  o = (o + 3) & ~(size_t)3;
  float* f = ws + o; o += (size_t)nN * 128;
  float* h = ws + o; o += (size_t)nN * 128;       // also reused as h3 (N x float4)
  float* nb_h = ws + o; o += (size_t)nN * 128;    // also reused as nb3
  int* ibase = (int*)(ws + o);
  int* count = ibase;                   // nN
  int* row_ptr = ibase + nN;            // nN+1 (+pad)
  int* cursor = row_ptr + nN + 4;       // nN
  int* partial = cursor + nN;           // 512
  int* csr_src = partial + 512;         // nE

  int nbScan = (nN + 255) / 256;

  hipMemsetAsync(count, 0, (size_t)nN * sizeof(int), stream);
  k_hist<<<(nE + 255) / 256, 256, 0, stream>>>(edges, count, nE);
  k_scan_part<<<nbScan, 256, 0, stream>>>(count, partial, nN);
  k_scan_mid<<<1, 512, 0, stream>>>(partial, row_ptr, nbScan, nN, nE);
  k_scan_out<<<nbScan, 256, 0, stream>>>(count, partial, row_ptr, cursor, invdeg, nN);
  k_fill<<<(nE + 255) / 256, 256, 0, stream>>>(edges, cursor, csr_src, nE);

  k_nbin<<<nbScan, 256, 0, stream>>>(row_ptr, csr_src, vert, vp, invdeg, nb_in, nN);
  k_layer0<<<(int)(((size_t)nN * 128 + 255) / 256), 256, 0, stream>>>(
      vert, vp, nb_in, W0s, W0n, b0, f, nN);

  for (int i = 0; i < 4; ++i) {
    const float* zi = z + (size_t)i * nN * 64;
    const float* Wn = Wbn + (size_t)i * 198 * 128;
    const float* Wsm = Wbs + (size_t)i * 198 * 128;
    const float* bi = bb + (size_t)i * 128;
    k_gemm<1><<<(nN + 31) / 32, 256, 0, stream>>>(
        f, h, zi, vert, vp, nullptr, Wn, nullptr, nN);
    k_gather128<<<(int)(((size_t)nN * 32 + 255) / 256), 256, 0, stream>>>(
        (const float4*)h, row_ptr, csr_src, invdeg, (float4*)nb_h, nN);
    k_gemm<0><<<(nN + 31) / 32, 256, 0, stream>>>(
        f, nullptr, zi, vert, vp, nb_h, Wsm, bi, nN);
  }

  k_final_h<<<(nN + 3) / 4, 256, 0, stream>>>(f, Wln, (float4*)h, nN);
  k_gather3<<<nbScan, 256, 0, stream>>>(
      (const float4*)h, row_ptr, csr_src, invdeg, (float4*)nb_h, nN);
  k_final_out<<<(nN + 3) / 4, 256, 0, stream>>>(
      f, Wls, (const float4*)nb_h, bl, (float*)d_out, nN);
}

// Round 4
// 681.689 us; speedup vs baseline: 4.9711x; 2.1216x over previous
//
#include <hip/hip_runtime.h>
#include <hip/hip_bf16.h>

// N=100000, E=600000, H=128, Z=64, IN=6. Mid layers: K=198 (pad->224), fused N=256
// MFMA bf16 GEMM computing [h = x@Wn | partial = x@Ws] in one pass.
// f and h live in bf16; partial in f32; epilogue fused into CSR gather.

typedef short short8v __attribute__((ext_vector_type(8)));
typedef float float4v __attribute__((ext_vector_type(4)));

static __device__ __forceinline__ unsigned short f2b(float x) {
  union { float f; unsigned u; } v; v.f = x;
  unsigned r = v.u + 0x7FFF + ((v.u >> 16) & 1);
  return (unsigned short)(r >> 16);
}
static __device__ __forceinline__ float b2f(unsigned short x) {
  union { unsigned u; float f; } v; v.u = ((unsigned)x) << 16;
  return v.f;
}

// ---------------- CSR build ----------------
__global__ __launch_bounds__(256) void k_hist(
    const int* __restrict__ edges, int* __restrict__ count, int nE) {
  int e = blockIdx.x * blockDim.x + threadIdx.x;
  if (e >= nE) return;
  atomicAdd(&count[edges[2 * e + 1]], 1);
}

__global__ __launch_bounds__(256) void k_scan_part(
    const int* __restrict__ count, int* __restrict__ partial, int nN) {
  __shared__ int s[256];
  int t = threadIdx.x;
  int n = blockIdx.x * 256 + t;
  s[t] = (n < nN) ? count[n] : 0;
  __syncthreads();
  for (int off = 128; off > 0; off >>= 1) {
    if (t < off) s[t] += s[t + off];
    __syncthreads();
  }
  if (t == 0) partial[blockIdx.x] = s[0];
}

__global__ __launch_bounds__(512) void k_scan_mid(
    int* __restrict__ partial, int* __restrict__ row_ptr, int nb, int nN, int nE) {
  __shared__ int s[512];
  int t = threadIdx.x;
  int v = (t < nb) ? partial[t] : 0;
  s[t] = v;
  __syncthreads();
  for (int off = 1; off < 512; off <<= 1) {
    int add = (t >= off) ? s[t - off] : 0;
    __syncthreads();
    s[t] += add;
    __syncthreads();
  }
  if (t < nb) partial[t] = s[t] - v;  // exclusive
  if (t == 0) row_ptr[nN] = nE;
}

__global__ __launch_bounds__(256) void k_scan_out(
    const int* __restrict__ count, const int* __restrict__ partial,
    int* __restrict__ row_ptr, int* __restrict__ cursor,
    float* __restrict__ invdeg, int nN) {
  __shared__ int s[256];
  int t = threadIdx.x;
  int n = blockIdx.x * 256 + t;
  int v = (n < nN) ? count[n] : 0;
  s[t] = v;
  __syncthreads();
  for (int off = 1; off < 256; off <<= 1) {
    int add = (t >= off) ? s[t - off] : 0;
    __syncthreads();
    s[t] += add;
    __syncthreads();
  }
  if (n < nN) {
    int excl = s[t] - v + partial[blockIdx.x];
    row_ptr[n] = excl;
    cursor[n] = excl;
    invdeg[n] = 1.0f / fmaxf((float)v, 1.0f);
  }
}

__global__ __launch_bounds__(256) void k_fill(
    const int* __restrict__ edges, int* __restrict__ cursor,
    int* __restrict__ csr_src, int nE) {
  int e = blockIdx.x * blockDim.x + threadIdx.x;
  if (e >= nE) return;
  int src = edges[2 * e], dst = edges[2 * e + 1];
  int pos = atomicAdd(&cursor[dst], 1);
  csr_src[pos] = src;
}

// ---------------- weight prep: Wt[i][col 256][k 224] bf16 ----------------
__global__ __launch_bounds__(256) void k_prepw(
    const float* __restrict__ Wbn, const float* __restrict__ Wbs,
    unsigned short* __restrict__ Wt) {
  int t = blockIdx.x * 256 + threadIdx.x;
  if (t >= 4 * 256 * 224) return;
  int k = t % 224;
  int c = (t / 224) % 256;
  int i = t / (224 * 256);
  float v = 0.f;
  if (k < 198)
    v = (c < 128) ? Wbn[((size_t)i * 198 + k) * 128 + c]
                  : Wbs[((size_t)i * 198 + k) * 128 + (c - 128)];
  Wt[t] = f2b(v);
}

// ---------------- input-feature aggregation (6 feats) ----------------
__global__ __launch_bounds__(256) void k_nbin(
    const int* __restrict__ row_ptr, const int* __restrict__ csr_src,
    const float* __restrict__ vert, const float* __restrict__ vp,
    const float* __restrict__ invdeg, float* __restrict__ nb_in, int nN) {
  int n = blockIdx.x * blockDim.x + threadIdx.x;
  if (n >= nN) return;
  float a[6] = {0, 0, 0, 0, 0, 0};
  int beg = row_ptr[n], end = row_ptr[n + 1];
  for (int j = beg; j < end; ++j) {
    int s = csr_src[j];
#pragma unroll
    for (int k = 0; k < 3; ++k) {
      a[k] += vert[s * 3 + k];
      a[3 + k] += vp[s * 3 + k];
    }
  }
  float inv = invdeg[n];
#pragma unroll
  for (int k = 0; k < 6; ++k) nb_in[n * 6 + k] = a[k] * inv;
}

// ---------------- layer 0 (K=12, writes bf16 f) ----------------
__global__ __launch_bounds__(256) void k_layer0(
    const float* __restrict__ vert, const float* __restrict__ vp,
    const float* __restrict__ nb_in, const float* __restrict__ W0s,
    const float* __restrict__ W0n, const float* __restrict__ b0,
    unsigned short* __restrict__ fb, int nN) {
  int t = blockIdx.x * blockDim.x + threadIdx.x;
  int n = t >> 7, hh = t & 127;
  if (n >= nN) return;
  float acc = b0[hh];
#pragma unroll
  for (int k = 0; k < 3; ++k) {
    acc += vert[n * 3 + k] * W0s[k * 128 + hh];
    acc += vp[n * 3 + k] * W0s[(3 + k) * 128 + hh];
    acc += nb_in[n * 6 + k] * W0n[k * 128 + hh];
    acc += nb_in[n * 6 + 3 + k] * W0n[(3 + k) * 128 + hh];
  }
  fb[(size_t)n * 128 + hh] = f2b(fmaxf(acc, 0.0f));
}

// ---------------- fused MFMA GEMM: [h | partial] = x @ [Wn | Ws] ----------------
// x row (K=224): [f(128) | z(64) | vert(3) vp(3) | 0-pad(26)]
// Block: 64 rows x 256 cols, 4 waves (wave w -> cols w*64..w*64+63).
__global__ __launch_bounds__(256) void k_mfma(
    const unsigned short* __restrict__ fb, const float* __restrict__ z,
    const float* __restrict__ vert, const float* __restrict__ vp,
    const unsigned short* __restrict__ Wt, float* __restrict__ partial,
    unsigned short* __restrict__ hb, int nN) {
  __shared__ unsigned short xs[64 * 232];  // pitch 232 -> <=2-way LDS bank aliasing
  int t = threadIdx.x;
  int n0 = blockIdx.x * 64;

  // stage f (cols 0..127), 16B per thread-iter
  for (int i = t; i < 64 * 16; i += 256) {
    int r = i >> 4, ck = (i & 15) * 8;
    int gn = min(n0 + r, nN - 1);
    *(short8v*)&xs[r * 232 + ck] = *(const short8v*)&fb[(size_t)gn * 128 + ck];
  }
  // stage z (cols 128..191), f32->bf16
  for (int i = t; i < 64 * 16; i += 256) {
    int r = i >> 4, ck = (i & 15) * 4;
    int gn = min(n0 + r, nN - 1);
    float4 v = *(const float4*)&z[(size_t)gn * 64 + ck];
    ushort4 o = {f2b(v.x), f2b(v.y), f2b(v.z), f2b(v.w)};
    *(ushort4*)&xs[r * 232 + 128 + ck] = o;
  }
  // stage in (cols 192..197) + zero pad (198..223), as pairs
  for (int i = t; i < 64 * 16; i += 256) {
    int r = i >> 4, p = i & 15;
    int c = 192 + 2 * p;
    int gn = min(n0 + r, nN - 1);
    float v0 = 0.f, v1 = 0.f;
    if (c < 198)   v0 = (c < 195) ? vert[gn * 3 + c - 192] : vp[gn * 3 + c - 195];
    if (c + 1 < 198) v1 = (c + 1 < 195) ? vert[gn * 3 + c - 191] : vp[gn * 3 + c - 194];
    ushort2 o = {f2b(v0), f2b(v1)};
    *(ushort2*)&xs[r * 232 + c] = o;
  }
  __syncthreads();

  int w = t >> 6, l = t & 63;
  int c0 = w * 64;
  int lr = l & 15;
  int lk = (l >> 4) * 8;

  float4v acc[4][4];
#pragma unroll
  for (int mt = 0; mt < 4; ++mt)
#pragma unroll
    for (int nt = 0; nt < 4; ++nt)
      acc[mt][nt] = (float4v){0.f, 0.f, 0.f, 0.f};

#pragma unroll
  for (int ks = 0; ks < 7; ++ks) {
    short8v a[4], b[4];
#pragma unroll
    for (int nt = 0; nt < 4; ++nt)
      b[nt] = *(const short8v*)&Wt[(size_t)(c0 + nt * 16 + lr) * 224 + ks * 32 + lk];
#pragma unroll
    for (int mt = 0; mt < 4; ++mt)
      a[mt] = *(const short8v*)&xs[(mt * 16 + lr) * 232 + ks * 32 + lk];
#pragma unroll
    for (int mt = 0; mt < 4; ++mt)
#pragma unroll
      for (int nt = 0; nt < 4; ++nt)
        acc[mt][nt] = __builtin_amdgcn_mfma_f32_16x16x32_bf16(
            a[mt], b[nt], acc[mt][nt], 0, 0, 0);
  }

  // store: C layout col=lane&15, row=(lane>>4)*4+j
  int rbase = (l >> 4) * 4;
#pragma unroll
  for (int mt = 0; mt < 4; ++mt) {
#pragma unroll
    for (int nt = 0; nt < 4; ++nt) {
      int col = c0 + nt * 16 + lr;
#pragma unroll
      for (int j = 0; j < 4; ++j) {
        int row = n0 + mt * 16 + rbase + j;
        if (row < nN) {
          float v = acc[mt][nt][j];
          if (col < 128) hb[(size_t)row * 128 + col] = f2b(v);
          else           partial[(size_t)row * 128 + (col - 128)] = v;
        }
      }
    }
  }
}

// ---------------- gather h + epilogue: f = relu(partial + invdeg*sum(h[src]) + b)
__global__ __launch_bounds__(256) void k_gather_ep(
    const unsigned short* __restrict__ hb, const int* __restrict__ row_ptr,
    const int* __restrict__ csr_src, const float* __restrict__ invdeg,
    const float* __restrict__ partial, const float* __restrict__ bias,
    unsigned short* __restrict__ fb, int nN) {
  int t = blockIdx.x * 256 + threadIdx.x;
  int n = t >> 5, c = t & 31;  // cols 4c..4c+3
  if (n >= nN) return;
  int beg = row_ptr[n], end = row_ptr[n + 1];
  float a0 = 0, a1 = 0, a2 = 0, a3 = 0;
  int j = beg;
  for (; j + 1 < end; j += 2) {
    int s0 = csr_src[j], s1 = csr_src[j + 1];
    ushort4 v0 = *(const ushort4*)&hb[(size_t)s0 * 128 + c * 4];
    ushort4 v1 = *(const ushort4*)&hb[(size_t)s1 * 128 + c * 4];
    a0 += b2f(v0.x) + b2f(v1.x);
    a1 += b2f(v0.y) + b2f(v1.y);
    a2 += b2f(v0.z) + b2f(v1.z);
    a3 += b2f(v0.w) + b2f(v1.w);
  }
  if (j < end) {
    int s0 = csr_src[j];
    ushort4 v0 = *(const ushort4*)&hb[(size_t)s0 * 128 + c * 4];
    a0 += b2f(v0.x); a1 += b2f(v0.y); a2 += b2f(v0.z); a3 += b2f(v0.w);
  }
  float inv = invdeg[n];
  float4 pv = *(const float4*)&partial[(size_t)n * 128 + c * 4];
  float4 bv = *(const float4*)&bias[c * 4];
  ushort4 o;
  o.x = f2b(fmaxf(pv.x + a0 * inv + bv.x, 0.f));
  o.y = f2b(fmaxf(pv.y + a1 * inv + bv.y, 0.f));
  o.z = f2b(fmaxf(pv.z + a2 * inv + bv.z, 0.f));
  o.w = f2b(fmaxf(pv.w + a3 * inv + bv.w, 0.f));
  *(ushort4*)&fb[(size_t)n * 128 + c * 4] = o;
}

// ---------------- final layer ----------------
__global__ __launch_bounds__(256) void k_final_h(
    const unsigned short* __restrict__ fb, const float* __restrict__ Wln,
    float4* __restrict__ h3, int nN) {
  int n = blockIdx.x * 4 + (threadIdx.x >> 6);
  int l = threadIdx.x & 63;
  if (n >= nN) return;
  float a0 = b2f(fb[(size_t)n * 128 + l]), a1 = b2f(fb[(size_t)n * 128 + 64 + l]);
  float p[3];
#pragma unroll
  for (int o = 0; o < 3; ++o)
    p[o] = a0 * Wln[l * 3 + o] + a1 * Wln[(64 + l) * 3 + o];
#pragma unroll
  for (int off = 32; off >= 1; off >>= 1) {
    p[0] += __shfl_xor(p[0], off);
    p[1] += __shfl_xor(p[1], off);
    p[2] += __shfl_xor(p[2], off);
  }
  if (l == 0) {
    float4 o = {p[0], p[1], p[2], 0.0f};
    h3[n] = o;
  }
}

__global__ __launch_bounds__(256) void k_gather3(
    const float4* __restrict__ h3, const int* __restrict__ row_ptr,
    const int* __restrict__ csr_src, const float* __restrict__ invdeg,
    float4* __restrict__ nb3, int nN) {
  int n = blockIdx.x * 256 + threadIdx.x;
  if (n >= nN) return;
  int beg = row_ptr[n], end = row_ptr[n + 1];
  float4 acc = {0, 0, 0, 0};
  for (int j = beg; j < end; ++j) {
    float4 v = h3[csr_src[j]];
    acc.x += v.x; acc.y += v.y; acc.z += v.z;
  }
  float inv = invdeg[n];
  float4 o = {acc.x * inv, acc.y * inv, acc.z * inv, 0.0f};
  nb3[n] = o;
}

__global__ __launch_bounds__(256) void k_final_out(
    const unsigned short* __restrict__ fb, const float* __restrict__ Wls,
    const float4* __restrict__ nb3, const float* __restrict__ bl,
    float* __restrict__ out, int nN) {
  int n = blockIdx.x * 4 + (threadIdx.x >> 6);
  int l = threadIdx.x & 63;
  if (n >= nN) return;
  float a0 = b2f(fb[(size_t)n * 128 + l]), a1 = b2f(fb[(size_t)n * 128 + 64 + l]);
  float p[3];
#pragma unroll
  for (int o = 0; o < 3; ++o)
    p[o] = a0 * Wls[l * 3 + o] + a1 * Wls[(64 + l) * 3 + o];
#pragma unroll
  for (int off = 32; off >= 1; off >>= 1) {
    p[0] += __shfl_xor(p[0], off);
    p[1] += __shfl_xor(p[1], off);
    p[2] += __shfl_xor(p[2], off);
  }
  if (l == 0) {
    float4 nv = nb3[n];
    out[n * 3 + 0] = p[0] + nv.x + bl[0];
    out[n * 3 + 1] = p[1] + nv.y + bl[1];
    out[n * 3 + 2] = p[2] + nv.z + bl[2];
  }
}

extern "C" void kernel_launch(void* const* d_in, const int* in_sizes, int n_in,
                              void* d_out, int out_size, void* d_ws, size_t ws_size,
                              hipStream_t stream) {
  const float* vert = (const float*)d_in[0];
  const int* edges = (const int*)d_in[1];
  const float* vp = (const float*)d_in[2];
  const float* z = (const float*)d_in[3];
  const float* W0s = (const float*)d_in[4];
  const float* W0n = (const float*)d_in[5];
  const float* b0 = (const float*)d_in[6];
  const float* Wbs = (const float*)d_in[7];
  const float* Wbn = (const float*)d_in[8];
  const float* bb = (const float*)d_in[9];
  const float* Wls = (const float*)d_in[10];
  const float* Wln = (const float*)d_in[11];
  const float* bl = (const float*)d_in[12];
  int nN = in_sizes[0] / 3;
  int nE = in_sizes[1] / 2;

  float* ws = (float*)d_ws;
  size_t o = 0;
  float* invdeg = ws + o; o += (size_t)nN;
  float* nb_in = ws + o; o += (size_t)nN * 6;
  o = (o + 3) & ~(size_t)3;
  float* partial = ws + o; o += (size_t)nN * 128;
  unsigned short* hb = (unsigned short*)(ws + o); o += (size_t)nN * 64;
  unsigned short* fb = (unsigned short*)(ws + o); o += (size_t)nN * 64;
  unsigned short* Wt = (unsigned short*)(ws + o); o += (size_t)4 * 256 * 224 / 2;
  float* h3 = ws + o; o += (size_t)nN * 4;
  float* nb3 = ws + o; o += (size_t)nN * 4;
  int* ibase = (int*)(ws + o);
  int* count = ibase;              // nN
  int* row_ptr = ibase + nN;       // nN+1 (+pad)
  int* cursor = row_ptr + nN + 4;  // nN
  int* pscan = cursor + nN;        // 512
  int* csr_src = pscan + 512;      // nE

  int nbScan = (nN + 255) / 256;

  hipMemsetAsync(count, 0, (size_t)nN * sizeof(int), stream);
  k_hist<<<(nE + 255) / 256, 256, 0, stream>>>(edges, count, nE);
  k_scan_part<<<nbScan, 256, 0, stream>>>(count, pscan, nN);
  k_scan_mid<<<1, 512, 0, stream>>>(pscan, row_ptr, nbScan, nN, nE);
  k_scan_out<<<nbScan, 256, 0, stream>>>(count, pscan, row_ptr, cursor, invdeg, nN);
  k_fill<<<(nE + 255) / 256, 256, 0, stream>>>(edges, cursor, csr_src, nE);
  k_prepw<<<(4 * 256 * 224 + 255) / 256, 256, 0, stream>>>(Wbn, Wbs, Wt);

  k_nbin<<<nbScan, 256, 0, stream>>>(row_ptr, csr_src, vert, vp, invdeg, nb_in, nN);
  k_layer0<<<(int)(((size_t)nN * 128 + 255) / 256), 256, 0, stream>>>(
      vert, vp, nb_in, W0s, W0n, b0, fb, nN);

  for (int i = 0; i < 4; ++i) {
    const float* zi = z + (size_t)i * nN * 64;
    k_mfma<<<(nN + 63) / 64, 256, 0, stream>>>(
        fb, zi, vert, vp, Wt + (size_t)i * 256 * 224, partial, hb, nN);
    k_gather_ep<<<(int)(((size_t)nN * 32 + 255) / 256), 256, 0, stream>>>(
        hb, row_ptr, csr_src, invdeg, partial, bb + (size_t)i * 128, fb, nN);
  }

  k_final_h<<<(nN + 3) / 4, 256, 0, stream>>>(fb, Wln, (float4*)h3, nN);
  k_gather3<<<nbScan, 256, 0, stream>>>(
      (const float4*)h3, row_ptr, csr_src, invdeg, (float4*)nb3, nN);
  k_final_out<<<(nN + 3) / 4, 256, 0, stream>>>(
      fb, Wls, (const float4*)nb3, bl, (float*)d_out, nN);
}